// Round 7
// baseline (784.566 us; speedup 1.0000x reference)
//
#include <hip/hip_runtime.h>
#include <hip/hip_bf16.h>
#include <math.h>
#include <stdint.h>

#define B_   2
#define T_   1024
#define HID_ 2048
#define H_   16
#define DK_  128
#define DV_  128
#define TS_  16     // timesteps staged per LDS tile in recurrence

typedef __bf16 bf16;
typedef __attribute__((ext_vector_type(8))) __bf16 bf16x8;
typedef __attribute__((ext_vector_type(4))) float f32x4;

typedef __attribute__((address_space(3))) uint32_t* lds_ptr_t;
typedef const __attribute__((address_space(1))) uint32_t* glb_ptr_t;

__device__ __forceinline__ float sigmoidf_(float x) {
    return 1.0f / (1.0f + __expf(-x));
}

// async global->LDS, 16B per lane. LDS base wave-uniform (HW: lane i ->
// base + 16*i); global address is per-lane.
__device__ __forceinline__ void ldg_to_lds16(const void* g, void* lds) {
    __builtin_amdgcn_global_load_lds((glb_ptr_t)(uintptr_t)g,
                                     (lds_ptr_t)(uintptr_t)lds, 16, 0, 0);
}

// DPP rotate-add: VALU-latency cross-lane. CTRL = 0x120 + n (row_ror:n).
template <int CTRL>
__device__ __forceinline__ float dpp_ror_add(float x) {
    int yi = __builtin_amdgcn_update_dpp(
        0, __builtin_bit_cast(int, x), CTRL, 0xF, 0xF, true);
    return x + __builtin_bit_cast(float, yi);
}
// all-reduce (sum) across the 16 lanes of a DPP row
__device__ __forceinline__ float row16_allreduce(float x) {
    x = dpp_ror_add<0x128>(x);   // ror 8
    x = dpp_ror_add<0x124>(x);   // ror 4
    x = dpp_ror_add<0x122>(x);   // ror 2
    x = dpp_ror_add<0x121>(x);   // ror 1
    return x;
}

// ---------------------------------------------------------------------------
// fp32 -> bf16 elementwise cast, 8 elems/thread
// ---------------------------------------------------------------------------
__global__ __launch_bounds__(256) void cast_bf16_kernel(
    const float* __restrict__ in, bf16* __restrict__ out)
{
    int i = blockIdx.x * 256 + threadIdx.x;
    float4 a = ((const float4*)in)[2 * i];
    float4 b = ((const float4*)in)[2 * i + 1];
    bf16x8 o;
    o[0] = (bf16)a.x; o[1] = (bf16)a.y; o[2] = (bf16)a.z; o[3] = (bf16)a.w;
    o[4] = (bf16)b.x; o[5] = (bf16)b.y; o[6] = (bf16)b.z; o[7] = (bf16)b.w;
    ((bf16x8*)out)[i] = o;
}

// ---------------------------------------------------------------------------
// W [K,N] fp32  ->  Wt [N,K] bf16 (transpose-cast). 32x32 tiles.
// ---------------------------------------------------------------------------
__global__ __launch_bounds__(256) void tcast_kernel(
    const float* __restrict__ W, bf16* __restrict__ Wt, int K, int N)
{
    __shared__ float tile[32][33];
    const int k0 = blockIdx.y * 32, n0 = blockIdx.x * 32;
    const int r = threadIdx.x >> 5, c = threadIdx.x & 31;
    #pragma unroll
    for (int i = 0; i < 4; ++i)
        tile[r + 8 * i][c] = W[(size_t)(k0 + r + 8 * i) * N + n0 + c];
    __syncthreads();
    #pragma unroll
    for (int i = 0; i < 4; ++i)
        Wt[(size_t)(n0 + r + 8 * i) * K + k0 + c] = (bf16)tile[c][r + 8 * i];
}

// ---------------------------------------------------------------------------
// Transpose-cast with row/col offset + sign into Wt with row-stride 256.
// ---------------------------------------------------------------------------
__global__ __launch_bounds__(256) void tcast_off_kernel(
    const float* __restrict__ W, bf16* __restrict__ Wt,
    int N, int noff, int koff, float sign)
{
    __shared__ float tile[32][33];
    const int k0 = blockIdx.y * 32, n0 = blockIdx.x * 32;
    const int r = threadIdx.x >> 5, c = threadIdx.x & 31;
    #pragma unroll
    for (int i = 0; i < 4; ++i)
        tile[r + 8 * i][c] = W[(size_t)(k0 + r + 8 * i) * N + n0 + c];
    __syncthreads();
    #pragma unroll
    for (int i = 0; i < 4; ++i)
        Wt[(size_t)(noff + n0 + r + 8 * i) * 256 + koff + k0 + c] =
            (bf16)(sign * tile[c][r + 8 * i]);
}

// ---------------------------------------------------------------------------
// bf16 MFMA GEMM: C[M,N] = A[M,K] @ Bt[N,K]^T (+bias). 128x128 tile, BK=32.
// ---------------------------------------------------------------------------
__global__ __launch_bounds__(256) void mfma_gemm_kernel(
    const bf16* __restrict__ A, const bf16* __restrict__ Bt,
    const float* __restrict__ bias, void* __restrict__ Cout,
    int M, int N, int Kfull, int lda, int ldc, int bf16out)
{
    __shared__ bf16 As[128 * 32];
    __shared__ bf16 Bs[128 * 32];

    const int tid  = threadIdx.x;
    const int w    = tid >> 6;
    const int lane = tid & 63;
    const int n0   = blockIdx.x * 128;
    const int m0   = blockIdx.y * 128;
    const int wm   = (w >> 1) * 64;
    const int wn   = (w & 1) * 64;

    const int lr = lane >> 2;
    const int lc = (lane & 3) * 8;

    f32x4 acc[4][4];
    #pragma unroll
    for (int i = 0; i < 4; ++i)
        #pragma unroll
        for (int j = 0; j < 4; ++j) acc[i][j] = (f32x4)0.0f;

    const bf16* ApL = As + (wm + (lane & 15)) * 32 + (lane >> 4) * 8;
    const bf16* BpL = Bs + (wn + (lane & 15)) * 32 + (lane >> 4) * 8;

    for (int k0 = 0; k0 < Kfull; k0 += 32) {
        #pragma unroll
        for (int i = 0; i < 2; ++i) {
            const int rr = (w * 2 + i) * 16 + lr;
            ldg_to_lds16(A  + (size_t)(m0 + rr) * lda   + k0 + lc, As + (w * 2 + i) * 512);
            ldg_to_lds16(Bt + (size_t)(n0 + rr) * Kfull + k0 + lc, Bs + (w * 2 + i) * 512);
        }
        __syncthreads();

        bf16x8 af[4], bfr[4];
        #pragma unroll
        for (int i = 0; i < 4; ++i) af[i]  = *(const bf16x8*)(ApL + i * 16 * 32);
        #pragma unroll
        for (int j = 0; j < 4; ++j) bfr[j] = *(const bf16x8*)(BpL + j * 16 * 32);
        #pragma unroll
        for (int i = 0; i < 4; ++i)
            #pragma unroll
            for (int j = 0; j < 4; ++j)
                acc[i][j] = __builtin_amdgcn_mfma_f32_16x16x32_bf16(
                    af[i], bfr[j], acc[i][j], 0, 0, 0);
        __syncthreads();
    }

    #pragma unroll
    for (int i = 0; i < 4; ++i) {
        const int row = m0 + wm + i * 16 + (lane >> 4) * 4;
        #pragma unroll
        for (int j = 0; j < 4; ++j) {
            const int col = n0 + wn + j * 16 + (lane & 15);
            const float bv = bias ? bias[col] : 0.0f;
            #pragma unroll
            for (int r = 0; r < 4; ++r) {
                float v = acc[i][j][r] + bv;
                if (bf16out) ((bf16*)Cout)[(size_t)(row + r) * ldc + col] = (bf16)v;
                else ((float*)Cout)[(size_t)(row + r) * ldc + col] = v;
            }
        }
    }
}

// ---------------------------------------------------------------------------
// Cast mid slice of mega-GEMM output (cols 6144..6527 of [M,6528]) -> bf16
// ---------------------------------------------------------------------------
__global__ __launch_bounds__(256) void midcast_kernel(
    const float* __restrict__ src, bf16* __restrict__ midb)
{
    int i = blockIdx.x * 256 + threadIdx.x;   // over 2048*96
    int m = i / 96, c4 = i - m * 96;
    float4 v = *(const float4*)(src + (size_t)m * 6528 + 6144 + c4 * 4);
    bf16 o[4] = {(bf16)v.x, (bf16)v.y, (bf16)v.z, (bf16)v.w};
    *(uint64_t*)(midb + (size_t)m * 384 + c4 * 4) = *(uint64_t*)o;
}

// ---------------------------------------------------------------------------
// Fused skinny GEMMs: bb/bd/lam = x @ {Wbb,Wbd,Wlam}  (N=16 each, K=2048).
// ---------------------------------------------------------------------------
__global__ __launch_bounds__(256) void skinny3_kernel(
    const float* __restrict__ x, const float* __restrict__ Wbb,
    const float* __restrict__ Wbd, const float* __restrict__ Wlam,
    float* __restrict__ bb, float* __restrict__ bd, float* __restrict__ lam)
{
    __shared__ float xs[16][128];
    __shared__ float wsh[128][48];
    const int m0  = blockIdx.x * 16;
    const int tid = threadIdx.x;
    const int r = tid >> 4, cg = tid & 15;
    float acc0 = 0.f, acc1 = 0.f, acc2 = 0.f;

    for (int k0 = 0; k0 < HID_; k0 += 128) {
        __syncthreads();
        #pragma unroll
        for (int i = 0; i < 2; ++i) {
            int f = tid + 256 * i;
            int rr = f >> 5, cc = (f & 31) * 4;
            *(float4*)&xs[rr][cc] = *(const float4*)(x + (size_t)(m0 + rr) * HID_ + k0 + cc);
        }
        #pragma unroll
        for (int i = 0; i < 2; ++i) {
            int f = tid + 256 * i;
            int kk = f >> 2, cc = (f & 3) * 4;
            *(float4*)&wsh[kk][cc]      = *(const float4*)(Wbb  + (size_t)(k0 + kk) * 16 + cc);
            *(float4*)&wsh[kk][16 + cc] = *(const float4*)(Wbd  + (size_t)(k0 + kk) * 16 + cc);
            *(float4*)&wsh[kk][32 + cc] = *(const float4*)(Wlam + (size_t)(k0 + kk) * 16 + cc);
        }
        __syncthreads();
        #pragma unroll 8
        for (int kk = 0; kk < 128; ++kk) {
            float xv = xs[r][kk];
            acc0 += xv * wsh[kk][cg];
            acc1 += xv * wsh[kk][16 + cg];
            acc2 += xv * wsh[kk][32 + cg];
        }
    }
    size_t o = (size_t)(m0 + r) * 16 + cg;
    bb[o] = acc0; bd[o] = acc1; lam[o] = acc2;
}

// ---------------------------------------------------------------------------
// Causal depthwise conv1d (K=4) + SiLU, + optional per-head l2norm.
// mode: 0 = silu only -> fp32 (v); 1 = + l2norm -> bf16 (k);
//       2 = + l2norm * DK^-0.5 -> bf16 (q)
// ---------------------------------------------------------------------------
__global__ __launch_bounds__(256) void conv_silu_kernel(
    const float* __restrict__ xin, int ldx, int coloff,
    const float* __restrict__ w,
    bf16* __restrict__ ybf, float* __restrict__ yf32, int mode)
{
    const int bt  = blockIdx.x;
    const int t   = bt & (T_ - 1);
    const int tid = threadIdx.x;
    const float* xr = xin + (size_t)bt * ldx + coloff;

    float val[8];
    #pragma unroll
    for (int jj = 0; jj < 8; ++jj) {
        int c = tid + 256 * jj;
        float4 wc = *(const float4*)(w + (size_t)c * 4);
        const float* xc = xr + c;
        float acc = wc.w * xc[0];
        if (t >= 1) acc += wc.z * xc[-ldx];
        if (t >= 2) acc += wc.y * xc[-2 * ldx];
        if (t >= 3) acc += wc.x * xc[-3 * ldx];
        val[jj] = acc * sigmoidf_(acc);
    }

    if (mode > 0) {
        __shared__ float red[4][8];
        const int wv = tid >> 6;
        #pragma unroll
        for (int jj = 0; jj < 8; ++jj) {
            float v2 = val[jj] * val[jj];
            #pragma unroll
            for (int m = 1; m < 64; m <<= 1) v2 += __shfl_xor(v2, m);
            if ((tid & 63) == 0) red[wv][jj] = v2;
        }
        __syncthreads();
        const int wb = (tid >> 7) * 2;
        #pragma unroll
        for (int jj = 0; jj < 8; ++jj) {
            float ss = red[wb][jj] + red[wb + 1][jj];
            float sc = rsqrtf(ss + 1e-6f);
            if (mode == 2) sc *= 0.08838834764831845f;     // DK^-0.5
            val[jj] *= sc;
        }
    }

    const size_t row = (size_t)bt * HID_;
    if (mode == 0) {
        #pragma unroll
        for (int jj = 0; jj < 8; ++jj)
            yf32[row + tid + 256 * jj] = val[jj];
    } else {
        #pragma unroll
        for (int jj = 0; jj < 8; ++jj)
            ybf[row + tid + 256 * jj] = (bf16)val[jj];
    }
}

// ---------------------------------------------------------------------------
// Decay gates, in place on gfgs [M,4096] (cols 0..2047 = gf, 2048.. = gs)
// ---------------------------------------------------------------------------
__global__ __launch_bounds__(256) void decay_gate_kernel(
    float* gfgs, const float* __restrict__ A_log,
    const float* __restrict__ dt_bias)
{
    size_t i = (size_t)blockIdx.x * 256 + threadIdx.x;   // over M*2048
    int c = (int)(i & (HID_ - 1));
    size_t m = i >> 11;
    int h = c >> 7;
    float* pf = gfgs + m * 4096 + c;
    float* ps = pf + 2048;
    float na = -__expf(A_log[h]);
    float db = dt_bias[c];
    float xf = *pf + db;
    float xs = *ps + db;
    float spf = (xf > 20.0f) ? xf : log1pf(__expf(xf));
    float sps = (xs > 20.0f) ? xs : log1pf(__expf(xs));
    *pf = __expf(na * spf);
    *ps = __expf(na * sps);
}

// ---------------------------------------------------------------------------
// Dual-state gated delta-rule recurrence, v5: 2 columns per lane.
// LDS-pipe issue was the v4 bound (~670 cyc/CU-step model vs 636 measured):
// halve wave count by doubling columns/lane, and halve k/q read bytes (bf16).
// Grid: 256 blocks: bx = sv*32 + bh; bh = b*16+h, sv = s*4+vc (vc: 32-col
// chunk). Block: 4 waves; wave w covers cols w*8..w*8+7; lane = colg*16+kseg
// (colg 0..3 -> col pair w*8+colg*2+{0,1}; kseg: 8 k-chans). S0[8]+S1[8]/lane.
// e fp32 swizzled (2-way banks); k/q bf16 linear (16B/lane = naturally 2-way).
// DPP row16 all-reduce per column (colg groups align with DPP rows).
// ---------------------------------------------------------------------------
__global__ __launch_bounds__(256) void fkda_kernel(
    const bf16* __restrict__ qp, const bf16* __restrict__ kp,
    const float* __restrict__ vp, const float* __restrict__ egf,
    const float* __restrict__ egs, int ldeg,
    const float* __restrict__ bbp, const float* __restrict__ bdp,
    float* __restrict__ ofp, float* __restrict__ osp)
{
    const int bx = blockIdx.x;
    const int bh = bx & 31;
    const int sv = bx >> 5;
    const int b  = bh >> 4;
    const int h  = bh & 15;
    const int s  = sv >> 2;
    const int vc = sv & 3;          // 32-column chunk

    const float* eg = s ? egs : egf;
    float*       op = s ? osp : ofp;
    const float  bsign = s ? -1.0f : 1.0f;

    const int tid   = threadIdx.x;
    const int lane  = tid & 63;
    const int w     = tid >> 6;
    const int kseg  = lane & 15;
    const int colg  = lane >> 4;
    const int cpair = w * 8 + colg * 2;     // column pair within 32-chunk

    const size_t base  = (size_t)b * T_ * HID_ + (size_t)h * DK_;
    const size_t baseg = (size_t)b * T_ * ldeg + (size_t)h * DK_;

    __shared__ float EG[TS_ * 128];     // 8 KB, swizzled
    __shared__ bf16  KK[TS_ * 128];     // 4 KB, linear rows of 128 bf16
    __shared__ bf16  QQ[TS_ * 128];     // 4 KB
    __shared__ float VV[TS_ * 32];      // 2 KB
    __shared__ float OT[TS_ * 32];      // 2 KB
    __shared__ float BT[TS_];

    float S0[8], S1[8];
    #pragma unroll
    for (int j = 0; j < 8; ++j) { S0[j] = 0.0f; S1[j] = 0.0f; }

    // EG staging swizzle map (v4-verified): slot l5<16 -> chans 8*l5..+3,
    // l5>=16 -> 8*(l5-16)+4..+7
    const int l5  = lane & 31;
    const int ttl = lane >> 5;
    const int cg  = (l5 < 16) ? (l5 * 8) : ((l5 - 16) * 8 + 4);
    const int sl  = kseg * 4;           // EG read slot word base

    // KK/QQ staging map: wave stages 4 rows w*4..w*4+3; lane -> row
    // w*4+(lane>>4), chan (lane&15)*8  (16B = 8 bf16 per lane)
    const int krow = w * 4 + (lane >> 4);
    const int kcol = (lane & 15) * 8;

    for (int t0 = 0; t0 < T_; t0 += TS_) {
        // ---- stage tile ----
        #pragma unroll
        for (int i = 0; i < 2; ++i) {
            int n  = w * 2 + i;
            int tt = n * 2 + ttl;
            ldg_to_lds16(eg + baseg + (size_t)(t0 + tt) * ldeg + cg, EG + n * 256);
        }
        {
            size_t g = base + (size_t)(t0 + krow) * HID_ + kcol;
            ldg_to_lds16(kp + g, KK + w * 512);
            ldg_to_lds16(qp + g, QQ + w * 512);
        }
        if (tid < 128) {       // V: 16t x 32cols fp32
            int tt = tid >> 3, vo = (tid & 7) * 4;
            size_t g = base + (size_t)(t0 + tt) * HID_ + vc * 32 + vo;
            ((float4*)VV)[tid] = *(const float4*)(vp + g);
        }
        if (tid < TS_) {
            size_t gi = ((size_t)b * T_ + t0 + tid) * H_ + h;
            BT[tid] = sigmoidf_(bbp[gi] + bsign * bdp[gi]);
        }
        __syncthreads();

        // ---- 16 sequential steps ----
        #pragma unroll
        for (int tt = 0; tt < TS_; ++tt) {
            float e[8];
            *(float4*)&e[0] = *(const float4*)(EG + tt * 128 + sl);
            *(float4*)&e[4] = *(const float4*)(EG + tt * 128 + 64 + sl);
            bf16x8 k8 = *(const bf16x8*)(KK + tt * 128 + kseg * 8);
            bf16x8 q8 = *(const bf16x8*)(QQ + tt * 128 + kseg * 8);
            float2 v2 = *(const float2*)(VV + tt * 32 + cpair);
            float btv = BT[tt];

            float kf[8], qf[8];
            #pragma unroll
            for (int j = 0; j < 8; ++j) { kf[j] = (float)k8[j]; qf[j] = (float)q8[j]; }

            float p0a = 0.f, p0b = 0.f, p1a = 0.f, p1b = 0.f;
            #pragma unroll
            for (int j = 0; j < 8; j += 2) {
                S0[j]     *= e[j];     p0a += kf[j]     * S0[j];
                S0[j + 1] *= e[j + 1]; p0b += kf[j + 1] * S0[j + 1];
                S1[j]     *= e[j];     p1a += kf[j]     * S1[j];
                S1[j + 1] *= e[j + 1]; p1b += kf[j + 1] * S1[j + 1];
            }
            float p0 = row16_allreduce(p0a + p0b);
            float p1 = row16_allreduce(p1a + p1b);

            float u0 = btv * (v2.x - p0);
            float u1 = btv * (v2.y - p1);

            float o0a = 0.f, o0b = 0.f, o1a = 0.f, o1b = 0.f;
            #pragma unroll
            for (int j = 0; j < 8; j += 2) {
                S0[j]     += kf[j]     * u0; o0a += qf[j]     * S0[j];
                S0[j + 1] += kf[j + 1] * u0; o0b += qf[j + 1] * S0[j + 1];
                S1[j]     += kf[j]     * u1; o1a += qf[j]     * S1[j];
                S1[j + 1] += kf[j + 1] * u1; o1b += qf[j + 1] * S1[j + 1];
            }
            float o0 = row16_allreduce(o0a + o0b);
            float o1 = row16_allreduce(o1a + o1b);

            if (kseg == 0) {
                OT[tt * 32 + cpair]     = o0;
                OT[tt * 32 + cpair + 1] = o1;
            }
        }
        __syncthreads();

        // ---- flush 16x32 outputs ----
        if (tid < 128) {
            int tt = tid >> 3, vo = (tid & 7) * 4;
            size_t g = base + (size_t)(t0 + tt) * HID_ + vc * 32 + vo;
            *(float4*)(op + g) = ((const float4*)OT)[tid];
        }
        // next staging writes EG/KK/QQ/VV (disjoint from OT); post-stage
        // barrier covers the OT flush reads before steps overwrite OT.
    }
}

// ---------------------------------------------------------------------------
// o = lam*o_f + (1-lam)*o_s -> per-head RMSNorm * onorm_w -> * sigmoid(gate)
// ---------------------------------------------------------------------------
__global__ __launch_bounds__(256) void mix_norm_gate_kernel(
    const float* of, const float* os, const float* lam_pre,
    const float* gate, const float* onorm_w, bf16* outp)
{
    const int bt  = blockIdx.x;
    const int tid = threadIdx.x;
    const size_t row = (size_t)bt * HID_;

    float val[8];
    #pragma unroll
    for (int jj = 0; jj < 8; ++jj) {
        int c = tid + 256 * jj;
        int h = c >> 7;
        float l = sigmoidf_(lam_pre[(size_t)bt * H_ + h]);
        val[jj] = l * of[row + c] + (1.0f - l) * os[row + c];
    }

    __shared__ float red[4][8];
    const int wv = tid >> 6;
    #pragma unroll
    for (int jj = 0; jj < 8; ++jj) {
        float v2 = val[jj] * val[jj];
        #pragma unroll
        for (int m = 1; m < 64; m <<= 1) v2 += __shfl_xor(v2, m);
        if ((tid & 63) == 0) red[wv][jj] = v2;
    }
    __syncthreads();
    const int wb = (tid >> 7) * 2;
    #pragma unroll
    for (int jj = 0; jj < 8; ++jj) {
        int c = tid + 256 * jj;
        float ss   = red[wb][jj] + red[wb + 1][jj];
        float mean = ss * (1.0f / 128.0f);
        float sc   = rsqrtf(mean + 1e-5f) * onorm_w[c & 127];
        float g    = sigmoidf_(gate[row + c]);
        outp[row + c] = (bf16)(val[jj] * sc * g);
    }
}

// ---------------------------------------------------------------------------
extern "C" void kernel_launch(void* const* d_in, const int* in_sizes, int n_in,
                              void* d_out, int out_size, void* d_ws, size_t ws_size,
                              hipStream_t stream) {
    const float* x       = (const float*)d_in[0];
    const float* Wq      = (const float*)d_in[1];
    const float* Wk      = (const float*)d_in[2];
    const float* Wv      = (const float*)d_in[3];
    const float* conv_wq = (const float*)d_in[4];
    const float* conv_wk = (const float*)d_in[5];
    const float* conv_wv = (const float*)d_in[6];
    const float* Wgb1    = (const float*)d_in[7];
    const float* Wgb2    = (const float*)d_in[8];
    const float* Wgd1    = (const float*)d_in[9];
    const float* Wgd2    = (const float*)d_in[10];
    const float* Wbb     = (const float*)d_in[11];
    const float* Wbd     = (const float*)d_in[12];
    const float* Wlam    = (const float*)d_in[13];
    const float* A_log   = (const float*)d_in[14];
    const float* dt_bias = (const float*)d_in[15];
    const float* Wg1     = (const float*)d_in[16];
    const float* Wg2     = (const float*)d_in[17];
    const float* bg2     = (const float*)d_in[18];
    const float* onorm_w = (const float*)d_in[19];
    const float* Wo      = (const float*)d_in[20];
    float* out = (float*)d_out;

    const size_t M = (size_t)B_ * T_;   // 2048

    float* ws = (float*)d_ws;
    size_t off = 0;
    auto alloc = [&](size_t nfloats) { float* p = ws + off; off += nfloats; return p; };

    float* bufQKV = alloc(M * 6528);              // mega preacts; later gfgs+gate
    float* wqkvTf = alloc((size_t)6528 * HID_ / 2);  // [6528,2048] bf16; reused
    float* xbf    = alloc(M * HID_ / 2);          // x bf16; later obf
    float* bufQf  = alloc(M * HID_ / 2);          // q bf16
    float* bufKf  = alloc(M * HID_ / 2);          // k bf16
    float* bufV   = alloc(M * HID_);              // v fp32
    float* bufC   = alloc(M * HID_);              // o_f
    float* bufD   = alloc(M * HID_);              // o_s
    float* midbf  = alloc(M * 384 / 2);           // midb bf16
    float* bb     = alloc(M * H_);
    float* bd     = alloc(M * H_);
    float* lamp   = alloc(M * H_);

    bf16* xb    = (bf16*)xbf;
    bf16* obf   = (bf16*)xbf;                     // reuse after mega-gemm
    bf16* bufQ  = (bf16*)bufQf;
    bf16* bufK  = (bf16*)bufKf;
    bf16* wqkvT = (bf16*)wqkvTf;
    bf16* woT   = wqkvT;                          // [2048,2048] after mega-gemm
    bf16* wcat  = wqkvT + (size_t)HID_ * HID_;    // [4096,256]
    bf16* wgate = wcat + (size_t)4096 * 256;      // [2048,128]
    bf16* midb  = (bf16*)midbf;
    float* gfgs = bufQKV;                         // [2048,4096] after conv
    float* bufE = bufQKV + M * 4096;              // gate [2048,2048]

    dim3 blk(256);
    auto gemm = [&](const bf16* A, const bf16* Bt, const float* bias, void* C,
                    int Mm, int Nn, int Kk, int lda, int ldc, int bf16out) {
        dim3 grid(Nn / 128, Mm / 128);
        mfma_gemm_kernel<<<grid, blk, 0, stream>>>(A, Bt, bias, C, Mm, Nn, Kk,
                                                   lda, ldc, bf16out);
    };
    auto tcast = [&](const float* W, bf16* Wt, int Kk, int Nn) {
        tcast_kernel<<<dim3(Nn / 32, Kk / 32), blk, 0, stream>>>(W, Wt, Kk, Nn);
    };

    // 0) cast x to bf16
    cast_bf16_kernel<<<dim3((unsigned)(M * HID_ / 8 / 256)), blk, 0, stream>>>(x, xb);

    // 1) mega projection: [Wq|Wk|Wv|Wgb1|Wgd1|Wg1], N=6528
    tcast(Wq,   wqkvT,                          HID_, HID_);
    tcast(Wk,   wqkvT + (size_t)2048 * HID_,    HID_, HID_);
    tcast(Wv,   wqkvT + (size_t)4096 * HID_,    HID_, HID_);
    tcast(Wgb1, wqkvT + (size_t)6144 * HID_,    HID_, 128);
    tcast(Wgd1, wqkvT + (size_t)6272 * HID_,    HID_, 128);
    tcast(Wg1,  wqkvT + (size_t)6400 * HID_,    HID_, 128);
    gemm(xb, wqkvT, nullptr, bufQKV, (int)M, 6528, HID_, HID_, 6528, 0);

    // 2) conv + silu (+ l2norm); q/k -> bf16, v -> fp32
    conv_silu_kernel<<<dim3(B_ * T_), blk, 0, stream>>>(bufQKV, 6528, 0,
        conv_wq, bufQ, nullptr, 2);
    conv_silu_kernel<<<dim3(B_ * T_), blk, 0, stream>>>(bufQKV, 6528, 2048,
        conv_wk, bufK, nullptr, 1);
    conv_silu_kernel<<<dim3(B_ * T_), blk, 0, stream>>>(bufQKV, 6528, 4096,
        conv_wv, nullptr, bufV, 0);

    // 3) mid slice -> bf16
    midcast_kernel<<<dim3((unsigned)(M * 96 / 256)), blk, 0, stream>>>(bufQKV, midb);

    // 4) skinny heads bb/bd/lam
    skinny3_kernel<<<dim3((unsigned)(M / 16)), blk, 0, stream>>>(
        x, Wbb, Wbd, Wlam, bb, bd, lamp);

    // 5) build concat weights and run fused gf/gs expand (N=4096, K=256)
    tcast_off_kernel<<<dim3(64, 4), blk, 0, stream>>>(Wgb2, wcat, HID_, 0,    0,   1.0f);
    tcast_off_kernel<<<dim3(64, 4), blk, 0, stream>>>(Wgd2, wcat, HID_, 0,    128, 1.0f);
    tcast_off_kernel<<<dim3(64, 4), blk, 0, stream>>>(Wgb2, wcat, HID_, 2048, 0,   1.0f);
    tcast_off_kernel<<<dim3(64, 4), blk, 0, stream>>>(Wgd2, wcat, HID_, 2048, 128, -1.0f);
    tcast(Wg2, wgate, 128, HID_);
    tcast(Wo,  woT,   HID_, HID_);
    gemm(midb,       wcat,  nullptr, gfgs, (int)M, 4096, 256, 384, 4096, 0);
    gemm(midb + 256, wgate, bg2,     bufE, (int)M, HID_, 128, 384, HID_, 0);

    // 6) decay gates in place on gfgs
    decay_gate_kernel<<<dim3((unsigned)(M * HID_ / 256)), blk, 0, stream>>>(
        gfgs, A_log, dt_bias);

    // 7) dual-state delta-rule recurrence (256 blocks, 2 cols/lane)
    fkda_kernel<<<dim3(256), blk, 0, stream>>>(bufQ, bufK, bufV,
        gfgs, gfgs + 2048, 4096, bb, bd, bufC, bufD);

    // 8) mix + rmsnorm + gate -> bf16
    mix_norm_gate_kernel<<<dim3(B_ * T_), blk, 0, stream>>>(
        bufC, bufD, lamp, bufE, onorm_w, obf);

    // 9) output projection
    gemm(obf, woT, nullptr, out, (int)M, HID_, HID_, HID_, HID_, 0);
}

// Round 8
// 769.717 us; speedup vs baseline: 1.0193x; 1.0193x over previous
//
#include <hip/hip_runtime.h>
#include <hip/hip_bf16.h>
#include <math.h>
#include <stdint.h>

#define B_   2
#define T_   1024
#define HID_ 2048
#define H_   16
#define DK_  128
#define DV_  128
#define TS_  16     // timesteps staged per LDS tile in recurrence

typedef __bf16 bf16;
typedef __attribute__((ext_vector_type(8))) __bf16 bf16x8;
typedef __attribute__((ext_vector_type(4))) float f32x4;

typedef __attribute__((address_space(3))) uint32_t* lds_ptr_t;
typedef const __attribute__((address_space(1))) uint32_t* glb_ptr_t;

__device__ __forceinline__ float sigmoidf_(float x) {
    return 1.0f / (1.0f + __expf(-x));
}

// async global->LDS, 16B per lane. LDS base wave-uniform (HW: lane i ->
// base + 16*i); global address is per-lane.
__device__ __forceinline__ void ldg_to_lds16(const void* g, void* lds) {
    __builtin_amdgcn_global_load_lds((glb_ptr_t)(uintptr_t)g,
                                     (lds_ptr_t)(uintptr_t)lds, 16, 0, 0);
}

// DPP rotate-add: VALU-latency cross-lane. CTRL = 0x120 + n (row_ror:n).
template <int CTRL>
__device__ __forceinline__ float dpp_ror_add(float x) {
    int yi = __builtin_amdgcn_update_dpp(
        0, __builtin_bit_cast(int, x), CTRL, 0xF, 0xF, true);
    return x + __builtin_bit_cast(float, yi);
}
__device__ __forceinline__ float row16_allreduce(float x) {
    x = dpp_ror_add<0x128>(x);   // ror 8
    x = dpp_ror_add<0x124>(x);   // ror 4
    x = dpp_ror_add<0x122>(x);   // ror 2
    x = dpp_ror_add<0x121>(x);   // ror 1
    return x;
}

// ---------------------------------------------------------------------------
// fp32 -> bf16 elementwise cast, 8 elems/thread
// ---------------------------------------------------------------------------
__global__ __launch_bounds__(256) void cast_bf16_kernel(
    const float* __restrict__ in, bf16* __restrict__ out)
{
    int i = blockIdx.x * 256 + threadIdx.x;
    float4 a = ((const float4*)in)[2 * i];
    float4 b = ((const float4*)in)[2 * i + 1];
    bf16x8 o;
    o[0] = (bf16)a.x; o[1] = (bf16)a.y; o[2] = (bf16)a.z; o[3] = (bf16)a.w;
    o[4] = (bf16)b.x; o[5] = (bf16)b.y; o[6] = (bf16)b.z; o[7] = (bf16)b.w;
    ((bf16x8*)out)[i] = o;
}

// ---------------------------------------------------------------------------
// Batched transpose-casts. Body: W [K,N] fp32 -> Wt [N,K] bf16, 32x32 tiles.
// ---------------------------------------------------------------------------
__device__ __forceinline__ void tcast_body(
    const float* __restrict__ W, bf16* __restrict__ Wt, int K, int N,
    int bx, int by, float sign)
{
    __shared__ float tile[32][33];
    const int k0 = by * 32, n0 = bx * 32;
    const int r = threadIdx.x >> 5, c = threadIdx.x & 31;
    #pragma unroll
    for (int i = 0; i < 4; ++i)
        tile[r + 8 * i][c] = W[(size_t)(k0 + r + 8 * i) * N + n0 + c];
    __syncthreads();
    #pragma unroll
    for (int i = 0; i < 4; ++i)
        Wt[(size_t)(n0 + r + 8 * i) * K + k0 + c] =
            (bf16)(sign * tile[c][r + 8 * i]);
}

// 4 big 2048x2048 weights: Wq,Wk,Wv -> wqkvT slices; Wo -> woT
__global__ __launch_bounds__(256) void tcast4_kernel(
    const float* Wq, const float* Wk, const float* Wv, const float* Wo,
    bf16* wqkvT, bf16* woT)
{
    const int z = blockIdx.z;
    const float* src = (z == 0) ? Wq : (z == 1) ? Wk : (z == 2) ? Wv : Wo;
    bf16* dst = (z < 3) ? (wqkvT + (size_t)z * HID_ * HID_) : woT;
    tcast_body(src, dst, HID_, HID_, blockIdx.x, blockIdx.y, 1.0f);
}

// 3 small K=2048,N=128 weights -> wqkvT cols 6144..6528
__global__ __launch_bounds__(256) void tcast_s3_kernel(
    const float* Wgb1, const float* Wgd1, const float* Wg1, bf16* wqkvT)
{
    const int z = blockIdx.z;
    const float* src = (z == 0) ? Wgb1 : (z == 1) ? Wgd1 : Wg1;
    bf16* dst = wqkvT + (size_t)(6144 + z * 128) * HID_;
    tcast_body(src, dst, HID_, 128, blockIdx.x, blockIdx.y, 1.0f);
}

// build wcat [4096,256] = [[Wgb2^T | Wgd2^T], [Wgb2^T | -Wgd2^T]]
__global__ __launch_bounds__(256) void tcast_off4_kernel(
    const float* Wgb2, const float* Wgd2, bf16* wcat)
{
    const int z = blockIdx.z;
    const float* src = (z & 1) ? Wgd2 : Wgb2;
    const int noff = (z >= 2) ? 2048 : 0;
    const int koff = (z & 1) ? 128 : 0;
    const float sign = (z == 3) ? -1.0f : 1.0f;
    __shared__ float tile[32][33];
    const int k0 = blockIdx.y * 32, n0 = blockIdx.x * 32;
    const int r = threadIdx.x >> 5, c = threadIdx.x & 31;
    #pragma unroll
    for (int i = 0; i < 4; ++i)
        tile[r + 8 * i][c] = src[(size_t)(k0 + r + 8 * i) * HID_ + n0 + c];
    __syncthreads();
    #pragma unroll
    for (int i = 0; i < 4; ++i)
        wcat[(size_t)(noff + n0 + r + 8 * i) * 256 + koff + k0 + c] =
            (bf16)(sign * tile[c][r + 8 * i]);
}

// Wg2 [128,2048] -> wgate [2048,128]
__global__ __launch_bounds__(256) void tcast_g_kernel(
    const float* Wg2, bf16* wgate)
{
    tcast_body(Wg2, wgate, 128, HID_, blockIdx.x, blockIdx.y, 1.0f);
}

// ---------------------------------------------------------------------------
// bf16 MFMA GEMM: C[M,N] = A[M,K] @ Bt[N,K]^T (+bias). 128x128 tile, BK=32.
// emode: 0 = fp32 out, 1 = bf16 out, 2 = decay epilogue (fp32):
//   out = exp(-exp(A_log[h]) * softplus(acc + dt_bias[c])), c = col&2047.
// ---------------------------------------------------------------------------
__global__ __launch_bounds__(256) void mfma_gemm_kernel(
    const bf16* __restrict__ A, const bf16* __restrict__ Bt,
    const float* __restrict__ bias, void* __restrict__ Cout,
    int M, int N, int Kfull, int lda, int ldc, int emode,
    const float* __restrict__ A_log, const float* __restrict__ dt_bias)
{
    __shared__ bf16 As[128 * 32];
    __shared__ bf16 Bs[128 * 32];

    const int tid  = threadIdx.x;
    const int w    = tid >> 6;
    const int lane = tid & 63;
    const int n0   = blockIdx.x * 128;
    const int m0   = blockIdx.y * 128;
    const int wm   = (w >> 1) * 64;
    const int wn   = (w & 1) * 64;

    const int lr = lane >> 2;
    const int lc = (lane & 3) * 8;

    f32x4 acc[4][4];
    #pragma unroll
    for (int i = 0; i < 4; ++i)
        #pragma unroll
        for (int j = 0; j < 4; ++j) acc[i][j] = (f32x4)0.0f;

    const bf16* ApL = As + (wm + (lane & 15)) * 32 + (lane >> 4) * 8;
    const bf16* BpL = Bs + (wn + (lane & 15)) * 32 + (lane >> 4) * 8;

    for (int k0 = 0; k0 < Kfull; k0 += 32) {
        #pragma unroll
        for (int i = 0; i < 2; ++i) {
            const int rr = (w * 2 + i) * 16 + lr;
            ldg_to_lds16(A  + (size_t)(m0 + rr) * lda   + k0 + lc, As + (w * 2 + i) * 512);
            ldg_to_lds16(Bt + (size_t)(n0 + rr) * Kfull + k0 + lc, Bs + (w * 2 + i) * 512);
        }
        __syncthreads();

        bf16x8 af[4], bfr[4];
        #pragma unroll
        for (int i = 0; i < 4; ++i) af[i]  = *(const bf16x8*)(ApL + i * 16 * 32);
        #pragma unroll
        for (int j = 0; j < 4; ++j) bfr[j] = *(const bf16x8*)(BpL + j * 16 * 32);
        #pragma unroll
        for (int i = 0; i < 4; ++i)
            #pragma unroll
            for (int j = 0; j < 4; ++j)
                acc[i][j] = __builtin_amdgcn_mfma_f32_16x16x32_bf16(
                    af[i], bfr[j], acc[i][j], 0, 0, 0);
        __syncthreads();
    }

    #pragma unroll
    for (int i = 0; i < 4; ++i) {
        const int row = m0 + wm + i * 16 + (lane >> 4) * 4;
        #pragma unroll
        for (int j = 0; j < 4; ++j) {
            const int col = n0 + wn + j * 16 + (lane & 15);
            float bv = 0.0f, na = 0.0f, db = 0.0f;
            if (bias) bv = bias[col];
            if (emode == 2) {
                int c = col & (HID_ - 1);
                na = -__expf(A_log[c >> 7]);
                db = dt_bias[c];
            }
            #pragma unroll
            for (int r = 0; r < 4; ++r) {
                float v = acc[i][j][r] + bv;
                size_t idx = (size_t)(row + r) * ldc + col;
                if (emode == 0) {
                    ((float*)Cout)[idx] = v;
                } else if (emode == 1) {
                    ((bf16*)Cout)[idx] = (bf16)v;
                } else {
                    float xx = v + db;
                    float sp = (xx > 20.0f) ? xx : log1pf(__expf(xx));
                    ((float*)Cout)[idx] = __expf(na * sp);
                }
            }
        }
    }
}

// ---------------------------------------------------------------------------
// Fused skinny GEMMs: bb/bd/lam = x @ {Wbb,Wbd,Wlam}  (N=16 each, K=2048).
// ---------------------------------------------------------------------------
__global__ __launch_bounds__(256) void skinny3_kernel(
    const float* __restrict__ x, const float* __restrict__ Wbb,
    const float* __restrict__ Wbd, const float* __restrict__ Wlam,
    float* __restrict__ bb, float* __restrict__ bd, float* __restrict__ lam)
{
    __shared__ float xs[16][128];
    __shared__ float wsh[128][48];
    const int m0  = blockIdx.x * 16;
    const int tid = threadIdx.x;
    const int r = tid >> 4, cg = tid & 15;
    float acc0 = 0.f, acc1 = 0.f, acc2 = 0.f;

    for (int k0 = 0; k0 < HID_; k0 += 128) {
        __syncthreads();
        #pragma unroll
        for (int i = 0; i < 2; ++i) {
            int f = tid + 256 * i;
            int rr = f >> 5, cc = (f & 31) * 4;
            *(float4*)&xs[rr][cc] = *(const float4*)(x + (size_t)(m0 + rr) * HID_ + k0 + cc);
        }
        #pragma unroll
        for (int i = 0; i < 2; ++i) {
            int f = tid + 256 * i;
            int kk = f >> 2, cc = (f & 3) * 4;
            *(float4*)&wsh[kk][cc]      = *(const float4*)(Wbb  + (size_t)(k0 + kk) * 16 + cc);
            *(float4*)&wsh[kk][16 + cc] = *(const float4*)(Wbd  + (size_t)(k0 + kk) * 16 + cc);
            *(float4*)&wsh[kk][32 + cc] = *(const float4*)(Wlam + (size_t)(k0 + kk) * 16 + cc);
        }
        __syncthreads();
        #pragma unroll 8
        for (int kk = 0; kk < 128; ++kk) {
            float xv = xs[r][kk];
            acc0 += xv * wsh[kk][cg];
            acc1 += xv * wsh[kk][16 + cg];
            acc2 += xv * wsh[kk][32 + cg];
        }
    }
    size_t o = (size_t)(m0 + r) * 16 + cg;
    bb[o] = acc0; bd[o] = acc1; lam[o] = acc2;
}

// ---------------------------------------------------------------------------
// Causal depthwise conv1d (K=4) + SiLU (+ per-head l2norm), all three slices
// in one launch: blockIdx.y: 0 = q (l2norm+scale, bf16), 1 = k (l2norm, bf16),
// 2 = v (silu only, fp32). Reads bf16 mega preacts (row stride 6528).
// ---------------------------------------------------------------------------
__global__ __launch_bounds__(256) void conv3_kernel(
    const bf16* __restrict__ qkvb,
    const float* __restrict__ wq, const float* __restrict__ wk,
    const float* __restrict__ wv,
    bf16* __restrict__ yq, bf16* __restrict__ yk, float* __restrict__ yv)
{
    const int bt  = blockIdx.x;
    const int y   = blockIdx.y;        // 0=q 1=k 2=v
    const int t   = bt & (T_ - 1);
    const int tid = threadIdx.x;
    const float* w = (y == 0) ? wq : (y == 1) ? wk : wv;
    const bf16* xr = qkvb + (size_t)bt * 6528 + y * 2048;

    float val[8];
    #pragma unroll
    for (int jj = 0; jj < 8; ++jj) {
        int c = tid + 256 * jj;
        float4 wc = *(const float4*)(w + (size_t)c * 4);
        const bf16* xc = xr + c;
        float acc = wc.w * (float)xc[0];
        if (t >= 1) acc += wc.z * (float)xc[-6528];
        if (t >= 2) acc += wc.y * (float)xc[-2 * 6528];
        if (t >= 3) acc += wc.x * (float)xc[-3 * 6528];
        val[jj] = acc * sigmoidf_(acc);
    }

    if (y < 2) {   // l2norm per head (128 chans)
        __shared__ float red[4][8];
        const int wv_ = tid >> 6;
        #pragma unroll
        for (int jj = 0; jj < 8; ++jj) {
            float v2 = val[jj] * val[jj];
            #pragma unroll
            for (int m = 1; m < 64; m <<= 1) v2 += __shfl_xor(v2, m);
            if ((tid & 63) == 0) red[wv_][jj] = v2;
        }
        __syncthreads();
        const int wb = (tid >> 7) * 2;
        #pragma unroll
        for (int jj = 0; jj < 8; ++jj) {
            float ss = red[wb][jj] + red[wb + 1][jj];
            float sc = rsqrtf(ss + 1e-6f);
            if (y == 0) sc *= 0.08838834764831845f;     // DK^-0.5
            val[jj] *= sc;
        }
        bf16* yo = (y == 0) ? yq : yk;
        const size_t row = (size_t)bt * HID_;
        #pragma unroll
        for (int jj = 0; jj < 8; ++jj)
            yo[row + tid + 256 * jj] = (bf16)val[jj];
    } else {
        const size_t row = (size_t)bt * HID_;
        #pragma unroll
        for (int jj = 0; jj < 8; ++jj)
            yv[row + tid + 256 * jj] = val[jj];
    }
}

// ---------------------------------------------------------------------------
// Dual-state gated delta-rule recurrence, v6 = v4 shape (512 blocks,
// 2 waves/SIMD) + bf16 k/q staging (4x b128/wave-step instead of 6).
// Grid: bx = sv*32 + bh; bh = b*16+h, sv = s*8+vc (vc: 16-col chunks).
// Block: 4 waves; wave = 4 cols (colb=w*4+(lane>>4)) x 16 ksegs (8 k-chans).
// e fp32 swizzled (2-way banks free); k/q bf16 linear (16B/lane, 2-way).
// ---------------------------------------------------------------------------
__global__ __launch_bounds__(256) void fkda_kernel(
    const bf16* __restrict__ qp, const bf16* __restrict__ kp,
    const float* __restrict__ vp, const float* __restrict__ egf,
    const float* __restrict__ egs, int ldeg,
    const float* __restrict__ bbp, const float* __restrict__ bdp,
    float* __restrict__ ofp, float* __restrict__ osp)
{
    const int bx = blockIdx.x;
    const int bh = bx & 31;
    const int sv = bx >> 5;
    const int b  = bh >> 4;
    const int h  = bh & 15;
    const int s  = sv >> 3;
    const int vc = sv & 7;          // 16-column chunk

    const float* eg = s ? egs : egf;
    float*       op = s ? osp : ofp;
    const float  bsign = s ? -1.0f : 1.0f;

    const int tid  = threadIdx.x;
    const int lane = tid & 63;
    const int w    = tid >> 6;
    const int kseg = lane & 15;
    const int colb = w * 4 + (lane >> 4);   // 0..15 within chunk

    const size_t base  = (size_t)b * T_ * HID_ + (size_t)h * DK_;
    const size_t baseg = (size_t)b * T_ * ldeg + (size_t)h * DK_;

    __shared__ float EG[TS_ * 128];     // 8 KB, swizzled
    __shared__ bf16  KK[TS_ * 128];     // 4 KB, linear rows of 128 bf16
    __shared__ bf16  QQ[TS_ * 128];     // 4 KB
    __shared__ float VV[TS_ * 16];      // 1 KB
    __shared__ float OT[TS_ * 16];      // 1 KB
    __shared__ float BT[TS_];

    float S[8];
    #pragma unroll
    for (int j = 0; j < 8; ++j) S[j] = 0.0f;

    // EG swizzle staging map (v4-verified)
    const int l5  = lane & 31;
    const int ttl = lane >> 5;
    const int cg  = (l5 < 16) ? (l5 * 8) : ((l5 - 16) * 8 + 4);
    const int sl  = kseg * 4;           // EG read slot word base

    // KK/QQ staging: wave w stages rows 4w..4w+3; lane -> row w*4+(lane>>4),
    // chan (lane&15)*8 (16B = 8 bf16)
    const int krow = w * 4 + (lane >> 4);
    const int kcol = (lane & 15) * 8;

    for (int t0 = 0; t0 < T_; t0 += TS_) {
        // ---- stage tile ----
        #pragma unroll
        for (int i = 0; i < 2; ++i) {
            int n  = w * 2 + i;
            int tt = n * 2 + ttl;
            ldg_to_lds16(eg + baseg + (size_t)(t0 + tt) * ldeg + cg, EG + n * 256);
        }
        {
            size_t g = base + (size_t)(t0 + krow) * HID_ + kcol;
            ldg_to_lds16(kp + g, KK + w * 512);
            ldg_to_lds16(qp + g, QQ + w * 512);
        }
        if (tid < 64) {       // V: 16t x 16cols fp32
            int tt = tid >> 2, vo = (tid & 3) * 4;
            size_t g = base + (size_t)(t0 + tt) * HID_ + vc * 16 + vo;
            ((float4*)VV)[tid] = *(const float4*)(vp + g);
        }
        if (tid < TS_) {
            size_t gi = ((size_t)b * T_ + t0 + tid) * H_ + h;
            BT[tid] = sigmoidf_(bbp[gi] + bsign * bdp[gi]);
        }
        __syncthreads();

        // ---- 16 sequential steps ----
        #pragma unroll
        for (int tt = 0; tt < TS_; ++tt) {
            float e[8];
            *(float4*)&e[0] = *(const float4*)(EG + tt * 128 + sl);
            *(float4*)&e[4] = *(const float4*)(EG + tt * 128 + 64 + sl);
            bf16x8 k8 = *(const bf16x8*)(KK + tt * 128 + kseg * 8);
            bf16x8 q8 = *(const bf16x8*)(QQ + tt * 128 + kseg * 8);
            float vcol = VV[tt * 16 + colb];
            float btv  = BT[tt];

            float kf[8], qf[8];
            #pragma unroll
            for (int j = 0; j < 8; ++j) { kf[j] = (float)k8[j]; qf[j] = (float)q8[j]; }

            float p0 = 0.0f, p1 = 0.0f;
            #pragma unroll
            for (int j = 0; j < 8; j += 2) {
                S[j]     *= e[j];     p0 += kf[j]     * S[j];
                S[j + 1] *= e[j + 1]; p1 += kf[j + 1] * S[j + 1];
            }
            float p = row16_allreduce(p0 + p1);

            float u = btv * (vcol - p);

            float o0 = 0.0f, o1 = 0.0f;
            #pragma unroll
            for (int j = 0; j < 8; j += 2) {
                S[j]     += kf[j]     * u; o0 += qf[j]     * S[j];
                S[j + 1] += kf[j + 1] * u; o1 += qf[j + 1] * S[j + 1];
            }
            float oo = row16_allreduce(o0 + o1);

            if (kseg == 0) OT[tt * 16 + colb] = oo;
        }
        __syncthreads();

        // ---- flush 16x16 outputs ----
        if (tid < 64) {
            int tt = tid >> 2, vo = (tid & 3) * 4;
            size_t g = base + (size_t)(t0 + tt) * HID_ + vc * 16 + vo;
            *(float4*)(op + g) = ((const float4*)OT)[tid];
        }
        // next staging writes EG/KK/QQ/VV (disjoint from OT); post-stage
        // barrier covers the OT flush reads before steps overwrite OT.
    }
}

// ---------------------------------------------------------------------------
// o = lam*o_f + (1-lam)*o_s -> per-head RMSNorm * onorm_w -> * sigmoid(gate)
// gate is bf16 now.
// ---------------------------------------------------------------------------
__global__ __launch_bounds__(256) void mix_norm_gate_kernel(
    const float* of, const float* os, const float* lam_pre,
    const bf16* gate, const float* onorm_w, bf16* outp)
{
    const int bt  = blockIdx.x;
    const int tid = threadIdx.x;
    const size_t row = (size_t)bt * HID_;

    float val[8];
    #pragma unroll
    for (int jj = 0; jj < 8; ++jj) {
        int c = tid + 256 * jj;
        int h = c >> 7;
        float l = sigmoidf_(lam_pre[(size_t)bt * H_ + h]);
        val[jj] = l * of[row + c] + (1.0f - l) * os[row + c];
    }

    __shared__ float red[4][8];
    const int wv = tid >> 6;
    #pragma unroll
    for (int jj = 0; jj < 8; ++jj) {
        float v2 = val[jj] * val[jj];
        #pragma unroll
        for (int m = 1; m < 64; m <<= 1) v2 += __shfl_xor(v2, m);
        if ((tid & 63) == 0) red[wv][jj] = v2;
    }
    __syncthreads();
    const int wb = (tid >> 7) * 2;
    #pragma unroll
    for (int jj = 0; jj < 8; ++jj) {
        int c = tid + 256 * jj;
        float ss   = red[wb][jj] + red[wb + 1][jj];
        float mean = ss * (1.0f / 128.0f);
        float sc   = rsqrtf(mean + 1e-5f) * onorm_w[c & 127];
        float g    = sigmoidf_((float)gate[row + c]);
        outp[row + c] = (bf16)(val[jj] * sc * g);
    }
}

// ---------------------------------------------------------------------------
extern "C" void kernel_launch(void* const* d_in, const int* in_sizes, int n_in,
                              void* d_out, int out_size, void* d_ws, size_t ws_size,
                              hipStream_t stream) {
    const float* x       = (const float*)d_in[0];
    const float* Wq      = (const float*)d_in[1];
    const float* Wk      = (const float*)d_in[2];
    const float* Wv      = (const float*)d_in[3];
    const float* conv_wq = (const float*)d_in[4];
    const float* conv_wk = (const float*)d_in[5];
    const float* conv_wv = (const float*)d_in[6];
    const float* Wgb1    = (const float*)d_in[7];
    const float* Wgb2    = (const float*)d_in[8];
    const float* Wgd1    = (const float*)d_in[9];
    const float* Wgd2    = (const float*)d_in[10];
    const float* Wbb     = (const float*)d_in[11];
    const float* Wbd     = (const float*)d_in[12];
    const float* Wlam    = (const float*)d_in[13];
    const float* A_log   = (const float*)d_in[14];
    const float* dt_bias = (const float*)d_in[15];
    const float* Wg1     = (const float*)d_in[16];
    const float* Wg2     = (const float*)d_in[17];
    const float* bg2     = (const float*)d_in[18];
    const float* onorm_w = (const float*)d_in[19];
    const float* Wo      = (const float*)d_in[20];
    float* out = (float*)d_out;

    const size_t M = (size_t)B_ * T_;   // 2048

    float* ws = (float*)d_ws;
    size_t off = 0;
    auto alloc = [&](size_t nfloats) { float* p = ws + off; off += nfloats; return p; };

    float* xbf    = alloc(M * HID_ / 2);             // x bf16; later obf
    float* qkvbf  = alloc(M * 6528 / 2);             // mega out bf16 [M,6528]
    float* wqkvTf = alloc((size_t)6528 * HID_ / 2);  // [6528,2048] bf16
    float* woTf   = alloc((size_t)HID_ * HID_ / 2);  // [2048,2048] bf16
    float* wcatf  = alloc((size_t)4096 * 256 / 2);   // [4096,256] bf16
    float* wgatef = alloc((size_t)HID_ * 128 / 2);   // [2048,128] bf16
    float* bufQf  = alloc(M * HID_ / 2);             // q bf16
    float* bufKf  = alloc(M * HID_ / 2);             // k bf16
    float* bufV   = alloc(M * HID_);                 // v fp32
    float* gfgs   = alloc(M * 4096);                 // exp(gf)|exp(gs) fp32
    float* bufEf  = alloc(M * HID_ / 2);             // gate bf16
    float* bufC   = alloc(M * HID_);                 // o_f
    float* bufD   = alloc(M * HID_);                 // o_s
    float* bb     = alloc(M * H_);
    float* bd     = alloc(M * H_);
    float* lamp   = alloc(M * H_);

    bf16* xb    = (bf16*)xbf;
    bf16* obf   = (bf16*)xbf;        // reuse after mega GEMM consumed xb
    bf16* qkvb  = (bf16*)qkvbf;
    bf16* wqkvT = (bf16*)wqkvTf;
    bf16* woT   = (bf16*)woTf;
    bf16* wcat  = (bf16*)wcatf;
    bf16* wgate = (bf16*)wgatef;
    bf16* bufQ  = (bf16*)bufQf;
    bf16* bufK  = (bf16*)bufKf;
    bf16* bufE  = (bf16*)bufEf;

    dim3 blk(256);
    auto gemm = [&](const bf16* A, const bf16* Bt, const float* bias, void* C,
                    int Mm, int Nn, int Kk, int lda, int ldc, int emode,
                    const float* a1, const float* a2) {
        dim3 grid(Nn / 128, Mm / 128);
        mfma_gemm_kernel<<<grid, blk, 0, stream>>>(A, Bt, bias, C, Mm, Nn, Kk,
                                                   lda, ldc, emode, a1, a2);
    };

    // 0) cast x to bf16
    cast_bf16_kernel<<<dim3((unsigned)(M * HID_ / 8 / 256)), blk, 0, stream>>>(x, xb);

    // 1) batched weight transpose-casts (4 launches total)
    tcast4_kernel<<<dim3(64, 64, 4), blk, 0, stream>>>(Wq, Wk, Wv, Wo, wqkvT, woT);
    tcast_s3_kernel<<<dim3(4, 64, 3), blk, 0, stream>>>(Wgb1, Wgd1, Wg1, wqkvT);
    tcast_off4_kernel<<<dim3(64, 4, 4), blk, 0, stream>>>(Wgb2, Wgd2, wcat);
    tcast_g_kernel<<<dim3(64, 4), blk, 0, stream>>>(Wg2, wgate);

    // 2) mega projection: [Wq|Wk|Wv|Wgb1|Wgd1|Wg1], N=6528 -> bf16
    gemm(xb, wqkvT, nullptr, qkvb, (int)M, 6528, HID_, HID_, 6528, 1,
         nullptr, nullptr);

    // 3) conv + silu (+ l2norm), one launch: q/k -> bf16, v -> fp32
    conv3_kernel<<<dim3(B_ * T_, 3), blk, 0, stream>>>(
        qkvb, conv_wq, conv_wk, conv_wv, bufQ, bufK, bufV);

    // 4) skinny heads bb/bd/lam
    skinny3_kernel<<<dim3((unsigned)(M / 16)), blk, 0, stream>>>(
        x, Wbb, Wbd, Wlam, bb, bd, lamp);

    // 5) fused gf/gs expand (N=4096, K=256) with decay epilogue -> gfgs fp32
    gemm(qkvb + 6144, wcat, nullptr, gfgs, (int)M, 4096, 256, 6528, 4096, 2,
         A_log, dt_bias);

    // 6) gate GEMM (N=2048, K=128) -> bf16
    gemm(qkvb + 6400, wgate, bg2, bufE, (int)M, HID_, 128, 6528, HID_, 1,
         nullptr, nullptr);

    // 7) dual-state delta-rule recurrence (512 blocks, 2 waves/SIMD)
    fkda_kernel<<<dim3(512), blk, 0, stream>>>(bufQ, bufK, bufV,
        gfgs, gfgs + 2048, 4096, bb, bd, bufC, bufD);

    // 8) mix + rmsnorm + gate -> bf16
    mix_norm_gate_kernel<<<dim3(B_ * T_), blk, 0, stream>>>(
        bufC, bufD, lamp, bufE, onorm_w, obf);

    // 9) output projection
    gemm(obf, woT, nullptr, out, (int)M, HID_, HID_, HID_, HID_, 0,
         nullptr, nullptr);
}